// Round 3
// baseline (1439.499 us; speedup 1.0000x reference)
//
#include <hip/hip_runtime.h>
#include <hip/hip_fp16.h>

typedef _Float16 half8 __attribute__((ext_vector_type(8)));
typedef _Float16 half4 __attribute__((ext_vector_type(4)));
typedef float floatx4 __attribute__((ext_vector_type(4)));

#define TT 512
#define EE 100
#define NBATCH 16

__device__ __forceinline__ float sigm(float x) {
    return __builtin_amdgcn_rcpf(1.0f + __expf(-x));
}
__device__ __forceinline__ float tanh_(float x) {
    // 2*sigmoid(2x) - 1  (saturates correctly at +/-1 for large |x|)
    return __builtin_amdgcn_rcpf(1.0f + __expf(-2.0f * x)) * 2.0f - 1.0f;
}
__device__ __forceinline__ half4 cvt4(float4 v) {
    half4 h; h[0] = (_Float16)v.x; h[1] = (_Float16)v.y; h[2] = (_Float16)v.z; h[3] = (_Float16)v.w;
    return h;
}

// 64 blocks x 256 threads (4 waves). Block = 16 batches, all 512 steps.
// Wave w: L1 units [32w,32w+32) all 4 gates (8 tiles), L2 units [16w,16w+16)
// all 4 gates (4 tiles) -> both cell updates fully in-register.
// LDS activations in MFMA B-fragment order [s][q][m][8]: 8-lane groups read
// 8 consecutive 16B chunks = 128B = all 32 banks once -> conflict-free.
extern "C" __global__ void __launch_bounds__(256, 1)
lstm_mfma2(const float* __restrict__ X,
           const float* __restrict__ W1ih, const float* __restrict__ W1hh,
           const float* __restrict__ b1i,  const float* __restrict__ b1h,
           const float* __restrict__ W2ih, const float* __restrict__ W2hh,
           const float* __restrict__ b2i,  const float* __restrict__ b2h,
           const float* __restrict__ fc1w, const float* __restrict__ fc1b,
           const float* __restrict__ fc2w, const float* __restrict__ fc2b,
           float* __restrict__ out)
{
    const int tid  = threadIdx.x;
    const int w    = tid >> 6;
    const int lane = tid & 63;
    const int q    = lane >> 4;
    const int m    = lane & 15;
    const int b0   = blockIdx.x * NBATCH;

    // fragment-order activation buffers: [buf][s][q][m][j]
    __shared__ __align__(16) _Float16 xb [2][4][4][16][8];   // K=128 (100 data + bias@100 + 0s)
    __shared__ __align__(16) _Float16 h1b[2][4][4][16][8];   // K=128
    __shared__ __align__(16) _Float16 h2b[2][2][4][16][8];   // K=64
    __shared__ float fca[NBATCH][32];

    // ---- zero-init LDS ----
    {
        _Float16* p = &xb[0][0][0][0][0];
        for (int i = tid; i < 2 * 4 * 4 * 16 * 8; i += 256) p[i] = (_Float16)0.0f;
        p = &h1b[0][0][0][0][0];
        for (int i = tid; i < 2 * 4 * 4 * 16 * 8; i += 256) p[i] = (_Float16)0.0f;
        p = &h2b[0][0][0][0][0];
        for (int i = tid; i < 2 * 2 * 4 * 16 * 8; i += 256) p[i] = (_Float16)0.0f;
    }
    __syncthreads();
    // bias-one column at k=100 -> s=3,qr=0,j=4 (both buffers, all batches)
    if (tid < 32) { const int bf = tid >> 4, mm = tid & 15; xb[bf][3][0][mm][4] = (_Float16)1.0f; }

    // ---- weight fragments (A-operand layout: row=m, k=32s+8q+j) ----
    half8 w1ihf[4][2][4], w1hhf[4][2][4], w2ihf[4][4], w2hhf[4][2];
    floatx4 bias2v[4];
#pragma unroll
    for (int g = 0; g < 4; ++g) {
#pragma unroll
        for (int u2 = 0; u2 < 2; ++u2) {
            const int r = g * 128 + 32 * w + 16 * u2 + m;
            const float bias = b1i[r] + b1h[r];
#pragma unroll
            for (int s = 0; s < 4; ++s) {
                half8 f;
#pragma unroll
                for (int j = 0; j < 8; ++j) {
                    const int k = 32 * s + 8 * q + j;
                    float v = 0.0f;
                    if (k < EE) v = W1ih[r * EE + k];
                    else if (k == EE) v = bias;   // pairs with xb[..][100]=1
                    f[j] = (_Float16)v;
                }
                w1ihf[g][u2][s] = f;
            }
#pragma unroll
            for (int s = 0; s < 4; ++s) {
                half8 f;
#pragma unroll
                for (int j = 0; j < 8; ++j) f[j] = (_Float16)W1hh[r * 128 + 32 * s + 8 * q + j];
                w1hhf[g][u2][s] = f;
            }
        }
    }
#pragma unroll
    for (int g = 0; g < 4; ++g) {
        const int r = g * 64 + 16 * w + m;
#pragma unroll
        for (int s = 0; s < 4; ++s) {
            half8 f;
#pragma unroll
            for (int j = 0; j < 8; ++j) f[j] = (_Float16)W2ih[r * 128 + 32 * s + 8 * q + j];
            w2ihf[g][s] = f;
        }
#pragma unroll
        for (int s = 0; s < 2; ++s) {
            half8 f;
#pragma unroll
            for (int j = 0; j < 8; ++j) f[j] = (_Float16)W2hh[r * 64 + 32 * s + 8 * q + j];
            w2hhf[g][s] = f;
        }
#pragma unroll
        for (int reg = 0; reg < 4; ++reg) {
            const int rr = g * 64 + 16 * w + 4 * q + reg;   // C row = 4q+reg
            bias2v[g][reg] = b2i[rr] + b2h[rr];
        }
    }

    // ---- x staging map: thread covers float4 slots {tid, tid+256} of 400 ----
    int gaddr[2], laddr[2];
    const bool val2 = (tid < 144);   // 400 - 256
#pragma unroll
    for (int u = 0; u < 2; ++u) {
        int f = tid + 256 * u; if (f >= 400) f = 0;
        const int n = f / 25, p = f - 25 * n, e0 = 4 * p;
        gaddr[u] = (b0 + n) * (TT * EE) + e0;
        const int s = e0 >> 5, qr = (e0 >> 3) & 3, j0 = e0 & 7;
        laddr[u] = ((s * 4 + qr) * 16 + n) * 8 + j0;       // half index in one buffer
    }
    _Float16* const xbase = &xb[0][0][0][0][0];            // buf stride 2048 halfs
    const _Float16* const h1base = &h1b[0][0][0][0][0];    // buf stride 2048
    const _Float16* const h2base = &h2b[0][0][0][0][0];    // buf stride 1024

    // stage x(0) into xb[0]; preload x(1) into regs
    {
        float4 v0 = *(const float4*)&X[gaddr[0]];
        *(half4*)&xbase[laddr[0]] = cvt4(v0);
        if (val2) {
            float4 v1 = *(const float4*)&X[gaddr[1]];
            *(half4*)&xbase[laddr[1]] = cvt4(v1);
        }
    }
    float4 xr0 = *(const float4*)&X[gaddr[0] + EE];
    float4 xr1 = val2 ? *(const float4*)&X[gaddr[1] + EE] : float4{0, 0, 0, 0};
    __syncthreads();

    floatx4 c1a[2] = {{0.f, 0.f, 0.f, 0.f}, {0.f, 0.f, 0.f, 0.f}};
    floatx4 c2a = {0.f, 0.f, 0.f, 0.f};

#pragma unroll 1
    for (int t = 0; t < TT; ++t) {
        const int cur = t & 1, nxt = cur ^ 1;

        // ---- phase A: L1 gates ----
        floatx4 a1[4][2];
#pragma unroll
        for (int g = 0; g < 4; ++g) { a1[g][0] = (floatx4){0.f,0.f,0.f,0.f}; a1[g][1] = (floatx4){0.f,0.f,0.f,0.f}; }
        {
            const _Float16* xc = xbase + cur * 2048 + q * 128 + m * 8;
#pragma unroll
            for (int s = 0; s < 4; ++s) {
                half8 bx = *(const half8*)(xc + s * 512);
#pragma unroll
                for (int g = 0; g < 4; ++g) {
                    a1[g][0] = __builtin_amdgcn_mfma_f32_16x16x32_f16(w1ihf[g][0][s], bx, a1[g][0], 0, 0, 0);
                    a1[g][1] = __builtin_amdgcn_mfma_f32_16x16x32_f16(w1ihf[g][1][s], bx, a1[g][1], 0, 0, 0);
                }
            }
            const _Float16* hp = h1base + nxt * 2048 + q * 128 + m * 8;
#pragma unroll
            for (int s = 0; s < 4; ++s) {
                half8 bh = *(const half8*)(hp + s * 512);
#pragma unroll
                for (int g = 0; g < 4; ++g) {
                    a1[g][0] = __builtin_amdgcn_mfma_f32_16x16x32_f16(w1hhf[g][0][s], bh, a1[g][0], 0, 0, 0);
                    a1[g][1] = __builtin_amdgcn_mfma_f32_16x16x32_f16(w1hhf[g][1][s], bh, a1[g][1], 0, 0, 0);
                }
            }
        }

        // ---- x pipeline: write x(t+1) regs->LDS[nxt]; issue x(t+2) loads ----
        {
            _Float16* xd = xbase + nxt * 2048;
            *(half4*)&xd[laddr[0]] = cvt4(xr0);
            if (val2) *(half4*)&xd[laddr[1]] = cvt4(xr1);
            const int tn = (t + 2 < TT) ? (t + 2) : (TT - 1);
            xr0 = *(const float4*)&X[gaddr[0] + tn * EE];
            if (val2) xr1 = *(const float4*)&X[gaddr[1] + tn * EE];
        }

        // ---- epilogue 1: L1 cell update (in-register) ----
#pragma unroll
        for (int u2 = 0; u2 < 2; ++u2) {
            half4 hv;
#pragma unroll
            for (int r = 0; r < 4; ++r) {
                const float iv = sigm(a1[0][u2][r]);
                const float fv = sigm(a1[1][u2][r]);
                const float gv = tanh_(a1[2][u2][r]);
                const float ov = sigm(a1[3][u2][r]);
                const float c  = fv * c1a[u2][r] + iv * gv;
                c1a[u2][r] = c;
                hv[r] = (_Float16)(ov * tanh_(c));
            }
            // unit u = 32w+16u2+4q+r -> s=w, qr=2u2+(q>>1), j=4(q&1)+r
            *(half4*)&h1b[cur][w][2 * u2 + (q >> 1)][m][4 * (q & 1)] = hv;
        }
        __syncthreads();

        // ---- phase B: L2 gates ----
        floatx4 a2[4] = { bias2v[0], bias2v[1], bias2v[2], bias2v[3] };
        {
            const _Float16* hc = h1base + cur * 2048 + q * 128 + m * 8;
#pragma unroll
            for (int s = 0; s < 4; ++s) {
                half8 bh = *(const half8*)(hc + s * 512);
#pragma unroll
                for (int g = 0; g < 4; ++g)
                    a2[g] = __builtin_amdgcn_mfma_f32_16x16x32_f16(w2ihf[g][s], bh, a2[g], 0, 0, 0);
            }
            const _Float16* h2p = h2base + nxt * 1024 + q * 128 + m * 8;
#pragma unroll
            for (int s = 0; s < 2; ++s) {
                half8 b2v = *(const half8*)(h2p + s * 512);
#pragma unroll
                for (int g = 0; g < 4; ++g)
                    a2[g] = __builtin_amdgcn_mfma_f32_16x16x32_f16(w2hhf[g][s], b2v, a2[g], 0, 0, 0);
            }
        }

        // ---- epilogue 2: L2 cell update (in-register) ----
        {
            half4 hv;
#pragma unroll
            for (int r = 0; r < 4; ++r) {
                const float iv = sigm(a2[0][r]);
                const float fv = sigm(a2[1][r]);
                const float gv = tanh_(a2[2][r]);
                const float ov = sigm(a2[3][r]);
                const float c  = fv * c2a[r] + iv * gv;
                c2a[r] = c;
                hv[r] = (_Float16)(ov * tanh_(c));
            }
            const int v = 2 * w + (q >> 1);   // u=16w+4q+r -> s2=v>>2, qr=v&3, j=4(q&1)+r
            *(half4*)&h2b[cur][v >> 2][v & 3][m][4 * (q & 1)] = hv;
        }
        __syncthreads();
    }

    // ---- FC head (h2 final is in h2b[1], fragment order) ----
#pragma unroll
    for (int rep = 0; rep < 2; ++rep) {
        const int idx = tid + 256 * rep;
        const int nb = idx >> 5, o = idx & 31;
        float s = fc1b[o];
#pragma unroll
        for (int k = 0; k < 64; ++k)
            s += fc1w[o * 64 + k] * (float)h2b[1][k >> 5][(k >> 3) & 3][nb][k & 7];
        fca[nb][o] = fmaxf(s, 0.0f);
    }
    __syncthreads();
    if (tid < NBATCH) {
        float s = fc2b[0];
#pragma unroll
        for (int k = 0; k < 32; ++k) s += fc2w[k] * fca[tid][k];
        out[b0 + tid] = sigm(s);
    }
}

extern "C" void kernel_launch(void* const* d_in, const int* in_sizes, int n_in,
                              void* d_out, int out_size, void* d_ws, size_t ws_size,
                              hipStream_t stream) {
    const float* X    = (const float*)d_in[0];
    const float* W1ih = (const float*)d_in[1];
    const float* W1hh = (const float*)d_in[2];
    const float* b1i  = (const float*)d_in[3];
    const float* b1h  = (const float*)d_in[4];
    const float* W2ih = (const float*)d_in[5];
    const float* W2hh = (const float*)d_in[6];
    const float* b2i  = (const float*)d_in[7];
    const float* b2h  = (const float*)d_in[8];
    const float* fc1w = (const float*)d_in[9];
    const float* fc1b = (const float*)d_in[10];
    const float* fc2w = (const float*)d_in[11];
    const float* fc2b = (const float*)d_in[12];

    hipLaunchKernelGGL(lstm_mfma2, dim3(1024 / NBATCH), dim3(256), 0, stream,
                       X, W1ih, W1hh, b1i, b1h, W2ih, W2hh, b2i, b2h,
                       fc1w, fc1b, fc2w, fc2b, (float*)d_out);
}

// Round 4
// 1099.530 us; speedup vs baseline: 1.3092x; 1.3092x over previous
//
#include <hip/hip_runtime.h>
#include <hip/hip_fp16.h>

typedef _Float16 half8 __attribute__((ext_vector_type(8)));
typedef _Float16 half4 __attribute__((ext_vector_type(4)));
typedef float floatx4 __attribute__((ext_vector_type(4)));

#define TT 512
#define EE 100
#define NBATCH 16
#define NBLK 64
#define WS_NEED ((size_t)NBLK * TT * 2048 * sizeof(_Float16))

__device__ __forceinline__ float sigm(float x) {
    return __builtin_amdgcn_rcpf(1.0f + __expf(-x));
}
__device__ __forceinline__ float tanh_(float x) {
    return __builtin_amdgcn_rcpf(1.0f + __expf(-2.0f * x)) * 2.0f - 1.0f;
}
__device__ __forceinline__ half4 cvt4(float4 v) {
    half4 h; h[0] = (_Float16)v.x; h[1] = (_Float16)v.y; h[2] = (_Float16)v.z; h[3] = (_Float16)v.w;
    return h;
}

// ---- pre-pass: X (fp32 [B][T][100]) -> fragment-ordered fp16 in d_ws ----
// Layout: xw[blk][t][c][m][8] halfs, c=k/8 (k padded to 128; k==100 is the
// bias-one column pairing with the bias column folded into W1ih fragments).
// One block per (blk,t); thread (c,m) writes 16B contiguous (fully coalesced).
extern "C" __global__ void __launch_bounds__(256)
xfrag_prep(const float* __restrict__ X, _Float16* __restrict__ xw)
{
    const int bt  = blockIdx.x;            // blk*512 + t
    const int blk = bt >> 9;
    const int t   = bt & (TT - 1);
    const int tid = threadIdx.x;
    const int c   = tid >> 4, m = tid & 15;
    const int k0  = 8 * c;
    half8 v;
#pragma unroll
    for (int j = 0; j < 8; ++j) v[j] = (_Float16)0.0f;
    const float* p = X + ((size_t)(blk * 16 + m) * TT + t) * EE + k0;
    if (k0 + 8 <= EE) {                    // c <= 11: full 8 floats
        float4 lo = *(const float4*)p;
        float4 hi = *(const float4*)(p + 4);
        v[0] = (_Float16)lo.x; v[1] = (_Float16)lo.y; v[2] = (_Float16)lo.z; v[3] = (_Float16)lo.w;
        v[4] = (_Float16)hi.x; v[5] = (_Float16)hi.y; v[6] = (_Float16)hi.z; v[7] = (_Float16)hi.w;
    } else if (k0 < EE) {                  // c == 12: k=96..99 + bias at k=100
        float4 lo = *(const float4*)p;
        v[0] = (_Float16)lo.x; v[1] = (_Float16)lo.y; v[2] = (_Float16)lo.z; v[3] = (_Float16)lo.w;
        v[4] = (_Float16)1.0f;
    }
    *(half8*)&xw[(size_t)bt * 2048 + c * 128 + m * 8] = v;
}

// ---- main: 64 blocks x 512 threads (8 waves), block = 16 batches, all T ----
// Wave w: L1 units [16w,16w+16) all 4 gates (4 tiles, in-register cell update).
// L2: waves 0-3 gates i,f / waves 4-7 gates g,o for units [16(w&3),+16);
// g,o activations cross via gob LDS (pad 68 -> conflict-free).
// Activations in B-fragment order [s][q][m][8] (reads 2-way = free).
// x fragments come straight from d_ws (USE_WS=1) prefetched 1 step ahead.
template<int USE_WS>
__global__ void __launch_bounds__(512, 1)
lstm_mfma3(const float* __restrict__ X, const _Float16* __restrict__ xw,
           const float* __restrict__ W1ih, const float* __restrict__ W1hh,
           const float* __restrict__ b1i,  const float* __restrict__ b1h,
           const float* __restrict__ W2ih, const float* __restrict__ W2hh,
           const float* __restrict__ b2i,  const float* __restrict__ b2h,
           const float* __restrict__ fc1w, const float* __restrict__ fc1b,
           const float* __restrict__ fc2w, const float* __restrict__ fc2b,
           float* __restrict__ out)
{
    const int tid  = threadIdx.x;
    const int w    = tid >> 6;
    const int lane = tid & 63;
    const int q    = lane >> 4;
    const int m    = lane & 15;
    const int b0   = blockIdx.x * NBATCH;
    const int gh   = w >> 2;      // 0: L2 gates i,f   1: L2 gates g,o
    const int p2   = w & 3;       // L2 unit-slice

    __shared__ __align__(16) _Float16 h1b[2][4][4][16][8];   // 8 KB
    __shared__ __align__(16) _Float16 h2b[2][2][4][16][8];   // 4 KB
    __shared__ __align__(16) _Float16 xb [2][4][4][16][8];   // 8 KB (fallback only)
    __shared__ __align__(16) _Float16 gob[2][16][68];        // 4.25 KB
    __shared__ float fca[NBATCH][32];

    {   // zero-init recurrent LDS state
        _Float16* p = &h1b[0][0][0][0][0];
        for (int i = tid; i < 2 * 2048; i += 512) p[i] = (_Float16)0.0f;
        p = &h2b[0][0][0][0][0];
        for (int i = tid; i < 2 * 1024; i += 512) p[i] = (_Float16)0.0f;
        if (!USE_WS) {
            p = &xb[0][0][0][0][0];
            for (int i = tid; i < 2 * 2048; i += 512) p[i] = (_Float16)0.0f;
        }
    }

    // ---- weight fragments ----
    half8 w1ihf[4][4], w1hhf[4][4], w2ihf[2][4], w2hhf[2][2];
    floatx4 bias2v[2];
#pragma unroll
    for (int g = 0; g < 4; ++g) {
        const int r = g * 128 + 16 * w + m;
        const float bias = b1i[r] + b1h[r];
#pragma unroll
        for (int s = 0; s < 4; ++s) {
            half8 f;
#pragma unroll
            for (int j = 0; j < 8; ++j) {
                const int k = 32 * s + 8 * q + j;
                float v = 0.0f;
                if (k < EE) v = W1ih[r * EE + k];
                else if (k == EE) v = bias;          // pairs with x bias-one column
                f[j] = (_Float16)v;
            }
            w1ihf[g][s] = f;
        }
#pragma unroll
        for (int s = 0; s < 4; ++s) {
            half8 f;
#pragma unroll
            for (int j = 0; j < 8; ++j) f[j] = (_Float16)W1hh[r * 128 + 32 * s + 8 * q + j];
            w1hhf[g][s] = f;
        }
    }
#pragma unroll
    for (int tau = 0; tau < 2; ++tau) {
        const int g = 2 * gh + tau;
        const int r = g * 64 + 16 * p2 + m;
#pragma unroll
        for (int s = 0; s < 4; ++s) {
            half8 f;
#pragma unroll
            for (int j = 0; j < 8; ++j) f[j] = (_Float16)W2ih[r * 128 + 32 * s + 8 * q + j];
            w2ihf[tau][s] = f;
        }
#pragma unroll
        for (int s = 0; s < 2; ++s) {
            half8 f;
#pragma unroll
            for (int j = 0; j < 8; ++j) f[j] = (_Float16)W2hh[r * 64 + 32 * s + 8 * q + j];
            w2hhf[tau][s] = f;
        }
#pragma unroll
        for (int reg = 0; reg < 4; ++reg) {
            const int rr = g * 64 + 16 * p2 + 4 * q + reg;
            bias2v[tau][reg] = b2i[rr] + b2h[rr];
        }
    }

    // ---- x source setup ----
    const _Float16* xwb = xw + (size_t)blockIdx.x * TT * 2048;
    const int foff = q * 128 + m * 8;          // fragment lane offset (halfs)
    half8 xcur[4], xnxt[4];

    int gaddr = 0, laddr = 0;
    bool xval = false;
    float4 xr = {0.f, 0.f, 0.f, 0.f};
    if (!USE_WS) {
        xval = tid < 400;
        const int f = xval ? tid : 0;
        const int n = f / 25, pp = f - 25 * n, e0 = 4 * pp;
        gaddr = (b0 + n) * (TT * EE) + e0;
        const int s = e0 >> 5, qr = (e0 >> 3) & 3, j0 = e0 & 7;
        laddr = ((s * 4 + qr) * 16 + n) * 8 + j0;
    }

    __syncthreads();
    if (USE_WS) {
#pragma unroll
        for (int s = 0; s < 4; ++s) xcur[s] = *(const half8*)&xwb[s * 512 + foff];
    } else {
        if (tid < 32) { const int bf = tid >> 4, mm = tid & 15; xb[bf][3][0][mm][4] = (_Float16)1.0f; }
        if (xval) {
            *(half4*)&(((_Float16*)xb)[laddr]) = cvt4(*(const float4*)&X[gaddr]);   // x(0)
            xr = *(const float4*)&X[gaddr + EE];                                    // x(1)
        }
    }
    __syncthreads();

    floatx4 c1 = {0.f, 0.f, 0.f, 0.f};
    floatx4 c2 = {0.f, 0.f, 0.f, 0.f};
    const int vv = 2 * w + (q >> 1);   // h1 fragment slot
    const int v2 = 2 * p2 + (q >> 1);  // h2 fragment slot
    const int jj = 4 * (q & 1);

#pragma unroll 1
    for (int t = 0; t < TT; ++t) {
        const int cur = t & 1, nxt = cur ^ 1;

        // prefetch x(t+1) fragments — a full step of latency before consumption
        if (USE_WS) {
            const int tn = (t + 1 < TT) ? (t + 1) : (TT - 1);
            const _Float16* xp = xwb + tn * 2048 + foff;
#pragma unroll
            for (int s = 0; s < 4; ++s) xnxt[s] = *(const half8*)(xp + s * 512);
        }

        // ---- phase A: L1 gates ----
        floatx4 a1[4];
#pragma unroll
        for (int g = 0; g < 4; ++g) a1[g] = (floatx4){0.f, 0.f, 0.f, 0.f};
        {
            const _Float16* xc = ((const _Float16*)xb) + cur * 2048 + foff;
#pragma unroll
            for (int s = 0; s < 4; ++s) {
                half8 bx = USE_WS ? xcur[s] : *(const half8*)(xc + s * 512);
#pragma unroll
                for (int g = 0; g < 4; ++g)
                    a1[g] = __builtin_amdgcn_mfma_f32_16x16x32_f16(w1ihf[g][s], bx, a1[g], 0, 0, 0);
            }
            const _Float16* hp = ((const _Float16*)h1b) + nxt * 2048 + foff;
#pragma unroll
            for (int s = 0; s < 4; ++s) {
                half8 bh = *(const half8*)(hp + s * 512);
#pragma unroll
                for (int g = 0; g < 4; ++g)
                    a1[g] = __builtin_amdgcn_mfma_f32_16x16x32_f16(w1hhf[g][s], bh, a1[g], 0, 0, 0);
            }
        }

        if (!USE_WS) {   // stage x(t+1), load x(t+2)
            if (xval) *(half4*)&(((_Float16*)xb)[nxt * 2048 + laddr]) = cvt4(xr);
            const int tn2 = (t + 2 < TT) ? (t + 2) : (TT - 1);
            if (xval) xr = *(const float4*)&X[gaddr + tn2 * EE];
        }

        // ---- epilogue 1: L1 cell update (in-register) ----
        {
            half4 hv;
#pragma unroll
            for (int r = 0; r < 4; ++r) {
                const float iv = sigm(a1[0][r]);
                const float fv = sigm(a1[1][r]);
                const float gv = tanh_(a1[2][r]);
                const float ov = sigm(a1[3][r]);
                const float c  = fv * c1[r] + iv * gv;
                c1[r] = c;
                hv[r] = (_Float16)(ov * tanh_(c));
            }
            *(half4*)&h1b[cur][vv >> 2][vv & 3][m][jj] = hv;
        }
        __syncthreads();

        // ---- phase B: L2 gates (2 per wave) ----
        floatx4 a2[2] = { bias2v[0], bias2v[1] };
        {
            const _Float16* hc = ((const _Float16*)h1b) + cur * 2048 + foff;
#pragma unroll
            for (int s = 0; s < 4; ++s) {
                half8 bh = *(const half8*)(hc + s * 512);
                a2[0] = __builtin_amdgcn_mfma_f32_16x16x32_f16(w2ihf[0][s], bh, a2[0], 0, 0, 0);
                a2[1] = __builtin_amdgcn_mfma_f32_16x16x32_f16(w2ihf[1][s], bh, a2[1], 0, 0, 0);
            }
            const _Float16* h2p = ((const _Float16*)h2b) + nxt * 1024 + foff;
#pragma unroll
            for (int s = 0; s < 2; ++s) {
                half8 b2v = *(const half8*)(h2p + s * 512);
                a2[0] = __builtin_amdgcn_mfma_f32_16x16x32_f16(w2hhf[0][s], b2v, a2[0], 0, 0, 0);
                a2[1] = __builtin_amdgcn_mfma_f32_16x16x32_f16(w2hhf[1][s], b2v, a2[1], 0, 0, 0);
            }
        }

        if (gh == 1) {   // activate g,o; hand to waves 0-3
            half4 tg, so;
#pragma unroll
            for (int r = 0; r < 4; ++r) {
                tg[r] = (_Float16)tanh_(a2[0][r]);
                so[r] = (_Float16)sigm(a2[1][r]);
            }
            *(half4*)&gob[0][m][16 * p2 + 4 * q] = tg;
            *(half4*)&gob[1][m][16 * p2 + 4 * q] = so;
        }
        if (USE_WS) {
#pragma unroll
            for (int s = 0; s < 4; ++s) xcur[s] = xnxt[s];
        }
        __syncthreads();

        if (gh == 0) {   // epilogue 2: c2/h2 update
            half4 tg = *(const half4*)&gob[0][m][16 * p2 + 4 * q];
            half4 so = *(const half4*)&gob[1][m][16 * p2 + 4 * q];
            half4 hv;
#pragma unroll
            for (int r = 0; r < 4; ++r) {
                const float c = sigm(a2[1][r]) * c2[r] + sigm(a2[0][r]) * (float)tg[r];
                c2[r] = c;
                hv[r] = (_Float16)((float)so[r] * tanh_(c));
            }
            *(half4*)&h2b[cur][v2 >> 2][v2 & 3][m][jj] = hv;
        }
        // next iteration's first barrier orders h2(t)/gob before reuse
    }
    __syncthreads();

    // ---- FC head (h2 final in h2b[1]) ----
    {
        const int nb = tid >> 5, o = tid & 31;   // 512 = 16 x 32 exactly
        float s = fc1b[o];
#pragma unroll
        for (int k = 0; k < 64; ++k)
            s += fc1w[o * 64 + k] * (float)h2b[1][k >> 5][(k >> 3) & 3][nb][k & 7];
        fca[nb][o] = fmaxf(s, 0.0f);
    }
    __syncthreads();
    if (tid < NBATCH) {
        float s = fc2b[0];
#pragma unroll
        for (int k = 0; k < 32; ++k) s += fc2w[k] * fca[tid][k];
        out[b0 + tid] = sigm(s);
    }
}

extern "C" void kernel_launch(void* const* d_in, const int* in_sizes, int n_in,
                              void* d_out, int out_size, void* d_ws, size_t ws_size,
                              hipStream_t stream) {
    const float* X    = (const float*)d_in[0];
    const float* W1ih = (const float*)d_in[1];
    const float* W1hh = (const float*)d_in[2];
    const float* b1i  = (const float*)d_in[3];
    const float* b1h  = (const float*)d_in[4];
    const float* W2ih = (const float*)d_in[5];
    const float* W2hh = (const float*)d_in[6];
    const float* b2i  = (const float*)d_in[7];
    const float* b2h  = (const float*)d_in[8];
    const float* fc1w = (const float*)d_in[9];
    const float* fc1b = (const float*)d_in[10];
    const float* fc2w = (const float*)d_in[11];
    const float* fc2b = (const float*)d_in[12];
    _Float16* xw = (_Float16*)d_ws;

    if (ws_size >= WS_NEED) {
        hipLaunchKernelGGL(xfrag_prep, dim3(NBLK * TT), dim3(256), 0, stream, X, xw);
        hipLaunchKernelGGL(lstm_mfma3<1>, dim3(NBLK), dim3(512), 0, stream,
                           X, xw, W1ih, W1hh, b1i, b1h, W2ih, W2hh, b2i, b2h,
                           fc1w, fc1b, fc2w, fc2b, (float*)d_out);
    } else {
        hipLaunchKernelGGL(lstm_mfma3<0>, dim3(NBLK), dim3(512), 0, stream,
                           X, xw, W1ih, W1hh, b1i, b1h, W2ih, W2hh, b2i, b2h,
                           fc1w, fc1b, fc2w, fc2b, (float*)d_out);
    }
}